// Round 15
// baseline (384.683 us; speedup 1.0000x reference)
//
#include <hip/hip_runtime.h>
#include <cmath>
#include <cfloat>

#define HW_ 16384

__device__ __forceinline__ unsigned f2key(float f){
    unsigned u = __float_as_uint(f);
    return u ^ ((u & 0x80000000u) ? 0xFFFFFFFFu : 0x80000000u);
}
__device__ __forceinline__ float key2f(unsigned k){
    unsigned u = (k & 0x80000000u) ? (k ^ 0x80000000u) : ~k;
    return __uint_as_float(u);
}
__device__ __forceinline__ unsigned short f2bf(float f){
    unsigned u = __float_as_uint(f);
    unsigned r = u + 0x7FFFu + ((u >> 16) & 1u);
    return (unsigned short)(r >> 16);
}
__device__ __forceinline__ float bf2f(unsigned short s){
    return __uint_as_float((unsigned)s << 16);
}
// deterministic value->bin map, identical codegen at all call sites (no contraction)
__device__ __forceinline__ int binof(float f){
    float t = __fsub_rn(f, 0.5f);
    return (int)__fmul_rn(t, 256.0f);
}
// packed helpers (bf16 pairs in u32; all pooled values >= 0 so u16 order == float order)
__device__ __forceinline__ unsigned pkmax(unsigned a, unsigned b){
    unsigned d;
    asm("v_pk_max_u16 %0, %1, %2" : "=v"(d) : "v"(a), "v"(b));
    return d;
}
__device__ __forceinline__ unsigned alignb(unsigned hi, unsigned lo){
    unsigned d;
    asm("v_alignbit_b32 %0, %1, %2, 16" : "=v"(d) : "v"(hi), "v"(lo));
    return d;
}
__device__ __forceinline__ unsigned cvtpk(float lo, float hi){
    unsigned d;
    asm("v_cvt_pk_bf16_f32 %0, %1, %2" : "=v"(d) : "v"(lo), "v"(hi));
    return d;
}
__device__ __forceinline__ unsigned wscan_incl(unsigned v, int lane){
    #pragma unroll
    for (int o = 1; o < 64; o <<= 1){
        unsigned u = __shfl_up(v, o);
        v += (lane >= o) ? u : 0u;
    }
    return v;
}

// ============================ K0: transpose W1 -> W1T[c][m] (runs once) ============================
__global__ __launch_bounds__(256) void k0_prep(
    const float* __restrict__ w1, float* __restrict__ W1T)
{
    int e = blockIdx.x * 256 + threadIdx.x;   // 0..4095
    int m = e >> 8, c = e & 255;
    W1T[c * 16 + m] = w1[m * 256 + c];
}

// ============================ K1f: windowed value-domain select + pools ============================
__global__ __launch_bounds__(512, 6) void k1f(
    const float* __restrict__ x,
    unsigned short* __restrict__ outp, unsigned short* __restrict__ m64g,
    float g1, float q2, float q3, float q4, float q5, float q6)
{
    __shared__ __align__(16) unsigned short C0[16384];
    __shared__ __align__(16) unsigned short H5s[8192];
    __shared__ unsigned hist[1024];
    __shared__ unsigned wsum[8];
    __shared__ unsigned redA[8], redB[8];
    __shared__ float candA[64], candB[64];
    __shared__ unsigned s_dA, s_dB, s_cloA, s_cloB, s_keyA, s_keyB;
    __shared__ unsigned s_b0, s_cntA, s_cntB;
    __shared__ float s_vA_f, s_vB_f;

    const int tid = threadIdx.x;
    const int lane = tid & 63;
    const int wid = tid >> 6;
    const unsigned bc = blockIdx.x;
    const float4* xp4 = (const float4*)(x + (size_t)bc * HW_);

    float v[32];

    // ---- P0: load x (floats stay in regs); windowed linear histogram ----
    hist[tid] = 0u; hist[tid + 512] = 0u;
    if (tid == 0){ s_b0 = 0u; s_cntA = 0u; s_cntB = 0u; }
    __syncthreads();

    int cntLo = 0;
    #pragma unroll
    for (int k = 0; k < 8; ++k){
        float4 q = xp4[tid + k * 512];
        v[4*k+0] = q.x; v[4*k+1] = q.y; v[4*k+2] = q.z; v[4*k+3] = q.w;
        #pragma unroll
        for (int e2 = 0; e2 < 4; ++e2){
            float f = v[4*k+e2];
            if (f < 0.5f) ++cntLo;
            else if (f < 4.5f) atomicAdd(&hist[binof(f)], 1u);
        }
    }
    {
        unsigned c = (unsigned)cntLo;
        #pragma unroll
        for (int o = 32; o > 0; o >>= 1) c += __shfl_down(c, o);
        if (lane == 0) atomicAdd(&s_b0, c);
    }
    __syncthreads();

    // ---- P1: find bins for ranks 15563/15564 ----
    const unsigned rA = 15563u, rB = 15564u;
    const unsigned B0 = s_b0;
    {
        unsigned h0 = hist[tid*2], h1 = hist[tid*2+1];
        unsigned part = h0 + h1;
        unsigned incl = wscan_incl(part, lane);
        if (lane == 63) wsum[wid] = incl;
        __syncthreads();
        unsigned off = B0;
        #pragma unroll
        for (int w = 0; w < 8; ++w) off += (w < wid) ? wsum[w] : 0u;
        unsigned phi = incl + off;
        unsigned plo = phi - part;
        if (rA >= plo && rA < phi){
            if (rA < plo + h0){ s_dA = tid*2;   s_cloA = plo; }
            else              { s_dA = tid*2+1; s_cloA = plo + h0; }
        }
        if (rB >= plo && rB < phi){
            if (rB < plo + h0){ s_dB = tid*2;   s_cloB = plo; }
            else              { s_dB = tid*2+1; s_cloB = plo + h0; }
        }
    }
    unsigned tot = B0;
    #pragma unroll
    for (int w = 0; w < 8; ++w) tot += wsum[w];
    bool fb = (rA < B0) || (rB >= tot);
    __syncthreads();

    unsigned dA = 0, dB = 0, cloA = 0, cloB = 0, nA = 0, nB = 0;
    if (!fb){
        dA = s_dA; dB = s_dB; cloA = s_cloA; cloB = s_cloB;
        nA = hist[dA]; nB = hist[dB];
        fb = (nA > 64u) || (nB > 64u);
    }

    if (!fb){
        // ---- compact target-bin members; exact stable rank-select on 2 waves ----
        #pragma unroll
        for (int e = 0; e < 32; ++e){
            float f = v[e];
            if (f >= 0.5f && f < 4.5f){
                int bq = binof(f);
                if (bq == (int)dA){
                    unsigned ix = atomicAdd(&s_cntA, 1u);
                    if (ix < 64u) candA[ix] = f;
                } else if (bq == (int)dB){
                    unsigned ix = atomicAdd(&s_cntB, 1u);
                    if (ix < 64u) candB[ix] = f;
                }
            }
        }
        __syncthreads();
        if (wid == 0 && lane < (int)nA){
            float mv = candA[lane];
            unsigned r = 0;
            for (unsigned j = 0; j < nA; ++j){
                float o = candA[j];
                if (o < mv || (o == mv && j < (unsigned)lane)) ++r;
            }
            if (r == rA - cloA) s_vA_f = mv;
        }
        if (wid == 1){
            bool same = (dA == dB);
            unsigned nn = same ? nA : nB;
            unsigned lr = rB - (same ? cloA : cloB);
            if (lane < (int)nn){
                float mv = same ? candA[lane] : candB[lane];
                unsigned r = 0;
                for (unsigned j = 0; j < nn; ++j){
                    float o = same ? candA[j] : candB[j];
                    if (o < mv || (o == mv && j < (unsigned)lane)) ++r;
                }
                if (r == lr) s_vB_f = mv;
            }
        }
        __syncthreads();
    } else {
        // ---- fallback: exact key-domain radix select (block-uniform, never taken for N(0,1)) ----
        hist[tid] = 0u; hist[tid + 512] = 0u;
        __syncthreads();
        #pragma unroll
        for (int e = 0; e < 32; ++e) atomicAdd(&hist[f2key(v[e]) >> 22], 1u);
        __syncthreads();
        unsigned ra = 15563u, rb = 15564u;
        unsigned prefVal = 0u, prefMask = 0u;
        bool done = false;
        {
            unsigned h0 = hist[tid*2], h1 = hist[tid*2+1];
            unsigned part = h0 + h1;
            unsigned incl = wscan_incl(part, lane);
            if (lane == 63) wsum[wid] = incl;
            __syncthreads();
            unsigned off = 0;
            #pragma unroll
            for (int w = 0; w < 8; ++w) off += (w < wid) ? wsum[w] : 0u;
            unsigned phi = incl + off;
            unsigned plo = phi - part;
            if (ra >= plo && ra < phi){
                if (ra < plo + h0){ s_dA = tid*2;   s_cloA = plo; }
                else              { s_dA = tid*2+1; s_cloA = plo + h0; }
            }
            if (rb >= plo && rb < phi){
                if (rb < plo + h0){ s_dB = tid*2;   s_cloB = plo; }
                else              { s_dB = tid*2+1; s_cloB = plo + h0; }
            }
            __syncthreads();
            unsigned dA2 = s_dA, dB2 = s_dB;
            if (dA2 != dB2){
                unsigned locA = 0u, locB = 0xFFFFFFFFu;
                #pragma unroll
                for (int e = 0; e < 32; ++e){
                    unsigned kk = f2key(v[e]);
                    unsigned d = kk >> 22;
                    if (d == dA2) locA = max(locA, kk);
                    if (d == dB2) locB = min(locB, kk);
                }
                #pragma unroll
                for (int o = 32; o > 0; o >>= 1){
                    locA = max(locA, __shfl_down(locA, o));
                    locB = min(locB, __shfl_down(locB, o));
                }
                if (lane == 0){ redA[wid] = locA; redB[wid] = locB; }
                __syncthreads();
                if (tid == 0){
                    unsigned a = redA[0], b = redB[0];
                    for (int w = 1; w < 8; ++w){ a = max(a, redA[w]); b = min(b, redB[w]); }
                    s_keyA = a; s_keyB = b;
                }
                __syncthreads();
                done = true;
            } else {
                prefVal = dA2 << 22; prefMask = 0x3FFu << 22;
                ra -= s_cloA; rb -= s_cloB;
                __syncthreads();
            }
        }
        if (!done){
            const int shifts[3] = {14, 6, 0};
            const int bitsv[3]  = {8, 8, 6};
            for (int lvl = 0; lvl < 3 && !done; ++lvl){
                int shift = shifts[lvl];
                unsigned nb = 1u << bitsv[lvl];
                unsigned msk = nb - 1u;
                if (tid < (int)nb) hist[tid] = 0u;
                __syncthreads();
                #pragma unroll
                for (int e = 0; e < 32; ++e){
                    unsigned kk = f2key(v[e]);
                    if ((kk & prefMask) == prefVal)
                        atomicAdd(&hist[(kk >> shift) & msk], 1u);
                }
                __syncthreads();
                unsigned part = (tid < (int)nb) ? hist[tid] : 0u;
                unsigned incl = wscan_incl(part, lane);
                if (lane == 63) wsum[wid] = incl;
                __syncthreads();
                unsigned off = 0;
                #pragma unroll
                for (int w = 0; w < 8; ++w) off += (w < wid) ? wsum[w] : 0u;
                unsigned phi = incl + off;
                unsigned plo = phi - part;
                if (tid < (int)nb){
                    if (ra >= plo && ra < phi){ s_dA = tid; s_cloA = plo; }
                    if (rb >= plo && rb < phi){ s_dB = tid; s_cloB = plo; }
                }
                __syncthreads();
                unsigned dA2 = s_dA, dB2 = s_dB;
                if (dA2 != dB2){
                    unsigned mA = prefMask | (msk << shift);
                    unsigned vAp = prefVal | (dA2 << shift);
                    unsigned vBp = prefVal | (dB2 << shift);
                    unsigned locA = 0u, locB = 0xFFFFFFFFu;
                    #pragma unroll
                    for (int e = 0; e < 32; ++e){
                        unsigned kk = f2key(v[e]);
                        if ((kk & mA) == vAp) locA = max(locA, kk);
                        if ((kk & mA) == vBp) locB = min(locB, kk);
                    }
                    #pragma unroll
                    for (int o = 32; o > 0; o >>= 1){
                        locA = max(locA, __shfl_down(locA, o));
                        locB = min(locB, __shfl_down(locB, o));
                    }
                    if (lane == 0){ redA[wid] = locA; redB[wid] = locB; }
                    __syncthreads();
                    if (tid == 0){
                        unsigned a = redA[0], b = redB[0];
                        for (int w = 1; w < 8; ++w){ a = max(a, redA[w]); b = min(b, redB[w]); }
                        s_keyA = a; s_keyB = b;
                    }
                    __syncthreads();
                    done = true;
                } else {
                    prefVal |= dA2 << shift;
                    prefMask |= msk << shift;
                    ra -= s_cloA; rb -= s_cloB;
                    if (lvl == 2){
                        if (tid == 0){ s_keyA = prefVal; s_keyB = prefVal; }
                        done = true;
                    }
                    __syncthreads();
                }
            }
        }
        if (tid == 0){ s_vA_f = key2f(s_keyA); s_vB_f = key2f(s_keyB); }
        __syncthreads();
    }

    float idxq = 0.95f * 16383.0f;
    float frac = idxq - floorf(idxq);
    const float thr = s_vA_f * (1.0f - frac) + s_vB_f * frac;

    // ---- P2: mask (from float regs) -> C0 packed bf16 ----
    #pragma unroll
    for (int k = 0; k < 8; ++k){
        int i = tid + k * 512;
        float f0 = v[4*k+0]; f0 = (f0 >= thr) ? f0 : 0.0f;
        float f1 = v[4*k+1]; f1 = (f1 >= thr) ? f1 : 0.0f;
        float f2 = v[4*k+2]; f2 = (f2 >= thr) ? f2 : 0.0f;
        float f3 = v[4*k+3]; f3 = (f3 >= thr) ? f3 : 0.0f;
        uint2 w; w.x = cvtpk(f0, f1); w.y = cvtpk(f2, f3);
        ((uint2*)C0)[i] = w;
    }
    __syncthreads();

    // ---- P3: row-band pool3 + outp + fused H5 ----
    {
        const unsigned* C0w = (const unsigned*)C0;
        unsigned* outp32 = (unsigned*)(outp + (size_t)bc * HW_);
        const int wc = lane;
        const int r0 = wid * 16;

        unsigned hmA, hmB, hmC, cB, cC;
        {
            int r = r0 - 1;
            if (r < 0){ hmA = 0u; }
            else {
                unsigned w = C0w[r*64 + wc];
                unsigned wl = __shfl_up(w, 1);
                unsigned wr = __shfl_down(w, 1);
                if (wc == 0)  wl = 0u;
                if (wc == 63) wr = 0u;
                hmA = pkmax(pkmax(alignb(w, wl), w), alignb(wr, w));
            }
        }
        {
            int r = r0;
            unsigned w = C0w[r*64 + wc];
            unsigned wl = __shfl_up(w, 1);
            unsigned wr = __shfl_down(w, 1);
            if (wc == 0)  wl = 0u;
            if (wc == 63) wr = 0u;
            hmB = pkmax(pkmax(alignb(w, wl), w), alignb(wr, w));
            cB = w;
        }
        #pragma unroll
        for (int rr = 0; rr < 16; ++rr){
            int r = r0 + rr;
            {
                int rn = r + 1;
                if (rn > 127){ hmC = 0u; cC = 0u; }
                else {
                    unsigned w = C0w[rn*64 + wc];
                    unsigned wl = __shfl_up(w, 1);
                    unsigned wr = __shfl_down(w, 1);
                    if (wc == 0)  wl = 0u;
                    if (wc == 63) wr = 0u;
                    hmC = pkmax(pkmax(alignb(w, wl), w), alignb(wr, w));
                    cC = w;
                }
            }
            unsigned p1 = pkmax(pkmax(hmA, hmB), hmC);
            float a0 = g1 * bf2f((unsigned short)(p1 & 0xFFFFu));
            float a1v = g1 * bf2f((unsigned short)(p1 >> 16));
            outp32[r*64 + wc] = pkmax(cB, cvtpk(a0, a1v));
            unsigned wjm1 = __shfl_up(p1, 1);
            unsigned wjp1 = __shfl_down(p1, 1);
            if (wc == 0)  wjm1 = 0u;
            if (wc == 63) wjp1 = 0u;
            unsigned s = pkmax(wjm1, p1);
            s = pkmax(s, s >> 16);
            s = pkmax(s, wjp1 & 0xFFFFu);
            H5s[r*64 + wc] = (unsigned short)s;
            hmA = hmB; hmB = hmC; cB = cC;
        }
    }
    __syncthreads();

    // ---- P5: vertical 5-tap stride-2 over H5 -> U; M regs = q2*u1 ----
    unsigned* U = (unsigned*)C0;
    unsigned* T = ((unsigned*)C0) + 2048;
    float mf[8];
    #pragma unroll
    for (int k = 0; k < 4; ++k){
        int q = tid + k * 512;
        int i = q >> 5, wj = q & 31;
        int rr = 2 * i;
        const unsigned* H5w = (const unsigned*)H5s;
        unsigned m = pkmax(H5w[rr*32 + wj], H5w[(rr+1)*32 + wj]);
        if (rr >= 1) m = pkmax(m, H5w[(rr-1)*32 + wj]);
        if (rr >= 2) m = pkmax(m, H5w[(rr-2)*32 + wj]);
        if (rr + 2 <= 127) m = pkmax(m, H5w[(rr+2)*32 + wj]);
        U[q] = m;
        mf[2*k]   = q2 * bf2f((unsigned short)(m & 0xFFFFu));
        mf[2*k+1] = q2 * bf2f((unsigned short)(m >> 16));
    }
    __syncthreads();

    // ---- P6: 4x unscaled pool3 on 64x64; fold scales into M regs ----
    const float gs[4] = {q3, q4, q5, q6};
    #pragma unroll
    for (int it = 0; it < 4; ++it){
        #pragma unroll
        for (int k = 0; k < 4; ++k){
            int q = tid + k * 512;
            unsigned w = U[q];
            unsigned wl = __shfl_up(w, 1);
            unsigned wr = __shfl_down(w, 1);
            if ((q & 31) == 0)  wl = 0u;
            if ((q & 31) == 31) wr = 0u;
            T[q] = pkmax(pkmax(alignb(w, wl), w), alignb(wr, w));
        }
        __syncthreads();
        #pragma unroll
        for (int k = 0; k < 4; ++k){
            int q = tid + k * 512;
            int r = q >> 5;
            unsigned w = T[q];
            if (r > 0)  w = pkmax(w, T[q - 32]);
            if (r < 63) w = pkmax(w, T[q + 32]);
            U[q] = w;
            mf[2*k]   = fmaxf(mf[2*k],   gs[it] * bf2f((unsigned short)(w & 0xFFFFu)));
            mf[2*k+1] = fmaxf(mf[2*k+1], gs[it] * bf2f((unsigned short)(w >> 16)));
        }
        __syncthreads();
    }

    // ---- P7: write m64 from M regs ----
    {
        unsigned* mp = (unsigned*)(m64g + (size_t)bc * 4096);
        #pragma unroll
        for (int k = 0; k < 4; ++k){
            int q = tid + k * 512;
            mp[q] = cvtpk(mf[2*k], mf[2*k+1]);
        }
    }
}

// ============================ K3: scalar MLP, SGPR weights, zero LDS ============================
__global__ __launch_bounds__(256, 6) void k3_sgpr(
    const float* __restrict__ x,
    const unsigned short* __restrict__ outp, const unsigned short* __restrict__ m64,
    const float* __restrict__ W1T,   // [256][16] f32 (w1 transposed)
    const float* __restrict__ w2,    // [256][16] f32
    const float* __restrict__ b1, const float* __restrict__ b2,
    float* __restrict__ y)
{
    const int tid = threadIdx.x;
    const int blk = blockIdx.x;
    const int b = blk >> 6;
    const int t = blk & 63;

    const int pix = t * 256 + tid;
    const int mi = (pix >> 8) * 64 + ((pix & 127) >> 1);
    const size_t base = (size_t)b * 256 * HW_;
    const size_t mbase = (size_t)b * 256 * 4096;

    float h[16];
    #pragma unroll
    for (int m = 0; m < 16; ++m) h[m] = 0.0f;

    #pragma unroll 4
    for (int c = 0; c < 256; ++c){
        float o  = bf2f(outp[base + (size_t)c * HW_ + pix]);
        float mo = bf2f(m64[mbase + (size_t)c * 4096 + mi]);
        o = fmaxf(o, mo);
        const float4* wr = (const float4*)(W1T + c * 16);   // uniform -> s_load
        float4 a0 = wr[0], a1 = wr[1], a2 = wr[2], a3 = wr[3];
        h[0]  = fmaf(a0.x, o, h[0]);  h[1]  = fmaf(a0.y, o, h[1]);
        h[2]  = fmaf(a0.z, o, h[2]);  h[3]  = fmaf(a0.w, o, h[3]);
        h[4]  = fmaf(a1.x, o, h[4]);  h[5]  = fmaf(a1.y, o, h[5]);
        h[6]  = fmaf(a1.z, o, h[6]);  h[7]  = fmaf(a1.w, o, h[7]);
        h[8]  = fmaf(a2.x, o, h[8]);  h[9]  = fmaf(a2.y, o, h[9]);
        h[10] = fmaf(a2.z, o, h[10]); h[11] = fmaf(a2.w, o, h[11]);
        h[12] = fmaf(a3.x, o, h[12]); h[13] = fmaf(a3.y, o, h[13]);
        h[14] = fmaf(a3.z, o, h[14]); h[15] = fmaf(a3.w, o, h[15]);
    }
    #pragma unroll
    for (int m = 0; m < 16; ++m) h[m] = fmaxf(h[m] + b1[m], 0.0f);

    #pragma unroll 4
    for (int c = 0; c < 256; ++c){
        const float4* wr = (const float4*)(w2 + c * 16);    // uniform -> s_load
        float4 a0 = wr[0], a1 = wr[1], a2 = wr[2], a3 = wr[3];
        float acc = b2[c];
        acc += a0.x * h[0]  + a0.y * h[1]  + a0.z * h[2]  + a0.w * h[3];
        acc += a1.x * h[4]  + a1.y * h[5]  + a1.z * h[6]  + a1.w * h[7];
        acc += a2.x * h[8]  + a2.y * h[9]  + a2.z * h[10] + a2.w * h[11];
        acc += a3.x * h[12] + a3.y * h[13] + a3.z * h[14] + a3.w * h[15];
        float R = 1.0f / (1.0f + __expf(-acc));
        float xv = x[base + (size_t)c * HW_ + pix];
        y[base + (size_t)c * HW_ + pix] = xv * R;
    }
}

extern "C" void kernel_launch(void* const* d_in, const int* in_sizes, int n_in,
                              void* d_out, int out_size, void* d_ws, size_t ws_size,
                              hipStream_t stream) {
    const float* x  = (const float*)d_in[0];
    const float* w1 = (const float*)d_in[1];
    const float* b1 = (const float*)d_in[2];
    const float* w2 = (const float*)d_in[3];
    const float* b2 = (const float*)d_in[4];
    float* y  = (float*)d_out;
    char* ws = (char*)d_ws;

    unsigned short* outp = (unsigned short*)ws;                 // 134 MB
    unsigned short* m64  = (unsigned short*)(ws + 134217728);   // 33.5 MB
    float*          W1T  = (float*)(ws + 167772160);            // 16 KB

    float g1 = 0.99f;
    float q2 = (float)std::pow(0.99, 3.0);
    float q3 = (float)std::pow(0.99, 7.0);
    float q4 = (float)std::pow(0.99, 15.0);
    float q5 = (float)std::pow(0.99, 31.0);
    float q6 = (float)std::pow(0.99, 63.0);

    k0_prep<<<16, 256, 0, stream>>>(w1, W1T);
    k1f<<<4096, 512, 0, stream>>>(x, outp, m64, g1, q2, q3, q4, q5, q6);
    k3_sgpr<<<1024, 256, 0, stream>>>(x, outp, m64, W1T, w2, b1, b2, y);
}

// Round 16
// 305.216 us; speedup vs baseline: 1.2604x; 1.2604x over previous
//
#include <hip/hip_runtime.h>
#include <cmath>
#include <cfloat>

#define HW_ 16384

__device__ __forceinline__ unsigned f2key(float f){
    unsigned u = __float_as_uint(f);
    return u ^ ((u & 0x80000000u) ? 0xFFFFFFFFu : 0x80000000u);
}
__device__ __forceinline__ float key2f(unsigned k){
    unsigned u = (k & 0x80000000u) ? (k ^ 0x80000000u) : ~k;
    return __uint_as_float(u);
}
__device__ __forceinline__ unsigned short f2bf(float f){
    unsigned u = __float_as_uint(f);
    unsigned r = u + 0x7FFFu + ((u >> 16) & 1u);
    return (unsigned short)(r >> 16);
}
__device__ __forceinline__ float bf2f(unsigned short s){
    return __uint_as_float((unsigned)s << 16);
}
// packed helpers (bf16 pairs in u32; all pooled values >= 0 so u16 order == float order)
__device__ __forceinline__ unsigned pkmax(unsigned a, unsigned b){
    unsigned d;
    asm("v_pk_max_u16 %0, %1, %2" : "=v"(d) : "v"(a), "v"(b));
    return d;
}
__device__ __forceinline__ unsigned alignb(unsigned hi, unsigned lo){
    unsigned d;
    asm("v_alignbit_b32 %0, %1, %2, 16" : "=v"(d) : "v"(hi), "v"(lo));
    return d;
}
__device__ __forceinline__ unsigned cvtpk(float lo, float hi){
    unsigned d;
    asm("v_cvt_pk_bf16_f32 %0, %1, %2" : "=v"(d) : "v"(lo), "v"(hi));
    return d;
}
__device__ __forceinline__ unsigned wscan_incl(unsigned v, int lane){
    #pragma unroll
    for (int o = 1; o < 64; o <<= 1){
        unsigned u = __shfl_up(v, o);
        v += (lane >= o) ? u : 0u;
    }
    return v;
}

// ============================ K0: transpose W1 -> W1T[c][m] (runs once) ============================
__global__ __launch_bounds__(256) void k0_prep(
    const float* __restrict__ w1, float* __restrict__ W1T)
{
    int e = blockIdx.x * 256 + threadIdx.x;   // 0..4095
    int m = e >> 8, c = e & 255;
    W1T[c * 16 + m] = w1[m * 256 + c];
}

// ============================ K1f: select + pools (R12 + split level-0 histogram) ============================
__global__ __launch_bounds__(512, 6) void k1f(
    const float* __restrict__ x,
    unsigned short* __restrict__ outp, unsigned short* __restrict__ m64g,
    float g1, float q2, float q3, float q4, float q5, float q6)
{
    __shared__ __align__(16) unsigned short C0[16384];
    __shared__ __align__(16) unsigned short H5s[8192];   // during select: histA/histB (8KB)
    __shared__ unsigned hist[1024];                       // refinement levels
    __shared__ unsigned wsum[8];
    __shared__ unsigned redA[8], redB[8];
    __shared__ unsigned s_dA, s_dB, s_cloA, s_cloB, s_keyA, s_keyB;

    unsigned* histA = (unsigned*)H5s;          // 1024 bins, even waves
    unsigned* histB = histA + 1024;            // 1024 bins, odd waves

    const int tid = threadIdx.x;
    const int lane = tid & 63;
    const int wid = tid >> 6;
    const unsigned bc = blockIdx.x;
    const float4* xp4 = (const float4*)(x + (size_t)bc * HW_);

    unsigned key[32];

    // ---- P0: init split hist, load x, build keys, 10-bit dual-bank histogram ----
    {
        unsigned* hb = (unsigned*)H5s;         // 2048 words total
        hb[tid] = 0u; hb[tid + 512] = 0u; hb[tid + 1024] = 0u; hb[tid + 1536] = 0u;
    }
    __syncthreads();
    {
        unsigned* myh = (wid & 1) ? histB : histA;
        #pragma unroll
        for (int k = 0; k < 8; ++k){
            float4 v = xp4[tid + k * 512];
            key[4*k+0] = f2key(v.x);
            key[4*k+1] = f2key(v.y);
            key[4*k+2] = f2key(v.z);
            key[4*k+3] = f2key(v.w);
            atomicAdd(&myh[key[4*k+0] >> 22], 1u);
            atomicAdd(&myh[key[4*k+1] >> 22], 1u);
            atomicAdd(&myh[key[4*k+2] >> 22], 1u);
            atomicAdd(&myh[key[4*k+3] >> 22], 1u);
        }
    }
    __syncthreads();

    unsigned rA = 15563u, rB = 15564u;
    unsigned prefVal = 0u, prefMask = 0u;
    bool done = false;

    {   // level 0: 10 bits (1024 bins, 2/thread), merged from banks
        unsigned h0 = histA[tid*2]   + histB[tid*2];
        unsigned h1 = histA[tid*2+1] + histB[tid*2+1];
        unsigned part = h0 + h1;
        unsigned incl = wscan_incl(part, lane);
        if (lane == 63) wsum[wid] = incl;
        __syncthreads();
        unsigned off = 0;
        #pragma unroll
        for (int w = 0; w < 8; ++w) off += (w < wid) ? wsum[w] : 0u;
        unsigned phi = incl + off;
        unsigned plo = phi - part;
        if (rA >= plo && rA < phi){
            if (rA < plo + h0){ s_dA = tid*2;   s_cloA = plo; }
            else              { s_dA = tid*2+1; s_cloA = plo + h0; }
        }
        if (rB >= plo && rB < phi){
            if (rB < plo + h0){ s_dB = tid*2;   s_cloB = plo; }
            else              { s_dB = tid*2+1; s_cloB = plo + h0; }
        }
        __syncthreads();
        unsigned dA = s_dA, dB = s_dB;
        if (dA != dB){
            unsigned locA = 0u, locB = 0xFFFFFFFFu;
            #pragma unroll
            for (int e = 0; e < 32; ++e){
                unsigned d = key[e] >> 22;
                if (d == dA) locA = max(locA, key[e]);
                if (d == dB) locB = min(locB, key[e]);
            }
            #pragma unroll
            for (int o = 32; o > 0; o >>= 1){
                locA = max(locA, __shfl_down(locA, o));
                locB = min(locB, __shfl_down(locB, o));
            }
            if (lane == 0){ redA[wid] = locA; redB[wid] = locB; }
            __syncthreads();
            if (tid == 0){
                unsigned a = redA[0], b = redB[0];
                for (int w = 1; w < 8; ++w){ a = max(a, redA[w]); b = min(b, redB[w]); }
                s_keyA = a; s_keyB = b;
            }
            __syncthreads();
            done = true;
        } else {
            prefVal = dA << 22; prefMask = 0x3FFu << 22;
            rA -= s_cloA; rB -= s_cloB;
            __syncthreads();
        }
    }

    if (!done){
        const int shifts[3] = {14, 6, 0};
        const int bitsv[3]  = {8, 8, 6};
        for (int lvl = 0; lvl < 3 && !done; ++lvl){
            int shift = shifts[lvl];
            unsigned nb = 1u << bitsv[lvl];
            unsigned msk = nb - 1u;
            if (tid < (int)nb) hist[tid] = 0u;
            __syncthreads();
            #pragma unroll
            for (int e = 0; e < 32; ++e){
                if ((key[e] & prefMask) == prefVal)
                    atomicAdd(&hist[(key[e] >> shift) & msk], 1u);
            }
            __syncthreads();
            unsigned part = (tid < (int)nb) ? hist[tid] : 0u;
            unsigned incl = wscan_incl(part, lane);
            if (lane == 63) wsum[wid] = incl;
            __syncthreads();
            unsigned off = 0;
            #pragma unroll
            for (int w = 0; w < 8; ++w) off += (w < wid) ? wsum[w] : 0u;
            unsigned phi = incl + off;
            unsigned plo = phi - part;
            if (tid < (int)nb){
                if (rA >= plo && rA < phi){ s_dA = tid; s_cloA = plo; }
                if (rB >= plo && rB < phi){ s_dB = tid; s_cloB = plo; }
            }
            __syncthreads();
            unsigned dA = s_dA, dB = s_dB;
            if (dA != dB){
                unsigned mA = prefMask | (msk << shift);
                unsigned vAp = prefVal | (dA << shift);
                unsigned vBp = prefVal | (dB << shift);
                unsigned locA = 0u, locB = 0xFFFFFFFFu;
                #pragma unroll
                for (int e = 0; e < 32; ++e){
                    if ((key[e] & mA) == vAp) locA = max(locA, key[e]);
                    if ((key[e] & mA) == vBp) locB = min(locB, key[e]);
                }
                #pragma unroll
                for (int o = 32; o > 0; o >>= 1){
                    locA = max(locA, __shfl_down(locA, o));
                    locB = min(locB, __shfl_down(locB, o));
                }
                if (lane == 0){ redA[wid] = locA; redB[wid] = locB; }
                __syncthreads();
                if (tid == 0){
                    unsigned a = redA[0], b = redB[0];
                    for (int w = 1; w < 8; ++w){ a = max(a, redA[w]); b = min(b, redB[w]); }
                    s_keyA = a; s_keyB = b;
                }
                __syncthreads();
                done = true;
            } else {
                prefVal |= dA << shift;
                prefMask |= msk << shift;
                rA -= s_cloA; rB -= s_cloB;
                if (lvl == 2){
                    if (tid == 0){ s_keyA = prefVal; s_keyB = prefVal; }
                    done = true;
                }
                __syncthreads();
            }
        }
    }

    float vlo = key2f(s_keyA);
    float vhi = key2f(s_keyB);
    float idxq = 0.95f * 16383.0f;
    float frac = idxq - floorf(idxq);
    const float thr = vlo * (1.0f - frac) + vhi * frac;

    // ---- P2: mask (regs/remat) -> C0 packed bf16 ----
    #pragma unroll
    for (int k = 0; k < 8; ++k){
        int i = tid + k * 512;
        float f0 = key2f(key[4*k+0]); f0 = (f0 >= thr) ? f0 : 0.0f;
        float f1 = key2f(key[4*k+1]); f1 = (f1 >= thr) ? f1 : 0.0f;
        float f2 = key2f(key[4*k+2]); f2 = (f2 >= thr) ? f2 : 0.0f;
        float f3 = key2f(key[4*k+3]); f3 = (f3 >= thr) ? f3 : 0.0f;
        uint2 w; w.x = cvtpk(f0, f1); w.y = cvtpk(f2, f3);
        ((uint2*)C0)[i] = w;
    }
    __syncthreads();

    // ---- P3: row-band pool3 + outp + fused H5 ----
    {
        const unsigned* C0w = (const unsigned*)C0;
        unsigned* outp32 = (unsigned*)(outp + (size_t)bc * HW_);
        const int wc = lane;
        const int r0 = wid * 16;

        unsigned hmA, hmB, hmC, cB, cC;
        {
            int r = r0 - 1;
            if (r < 0){ hmA = 0u; }
            else {
                unsigned w = C0w[r*64 + wc];
                unsigned wl = __shfl_up(w, 1);
                unsigned wr = __shfl_down(w, 1);
                if (wc == 0)  wl = 0u;
                if (wc == 63) wr = 0u;
                hmA = pkmax(pkmax(alignb(w, wl), w), alignb(wr, w));
            }
        }
        {
            int r = r0;
            unsigned w = C0w[r*64 + wc];
            unsigned wl = __shfl_up(w, 1);
            unsigned wr = __shfl_down(w, 1);
            if (wc == 0)  wl = 0u;
            if (wc == 63) wr = 0u;
            hmB = pkmax(pkmax(alignb(w, wl), w), alignb(wr, w));
            cB = w;
        }
        #pragma unroll
        for (int rr = 0; rr < 16; ++rr){
            int r = r0 + rr;
            {
                int rn = r + 1;
                if (rn > 127){ hmC = 0u; cC = 0u; }
                else {
                    unsigned w = C0w[rn*64 + wc];
                    unsigned wl = __shfl_up(w, 1);
                    unsigned wr = __shfl_down(w, 1);
                    if (wc == 0)  wl = 0u;
                    if (wc == 63) wr = 0u;
                    hmC = pkmax(pkmax(alignb(w, wl), w), alignb(wr, w));
                    cC = w;
                }
            }
            unsigned p1 = pkmax(pkmax(hmA, hmB), hmC);
            float a0 = g1 * bf2f((unsigned short)(p1 & 0xFFFFu));
            float a1v = g1 * bf2f((unsigned short)(p1 >> 16));
            outp32[r*64 + wc] = pkmax(cB, cvtpk(a0, a1v));
            unsigned wjm1 = __shfl_up(p1, 1);
            unsigned wjp1 = __shfl_down(p1, 1);
            if (wc == 0)  wjm1 = 0u;
            if (wc == 63) wjp1 = 0u;
            unsigned s = pkmax(wjm1, p1);
            s = pkmax(s, s >> 16);
            s = pkmax(s, wjp1 & 0xFFFFu);
            H5s[r*64 + wc] = (unsigned short)s;
            hmA = hmB; hmB = hmC; cB = cC;
        }
    }
    __syncthreads();

    // ---- P5: vertical 5-tap stride-2 over H5 -> U; M regs = q2*u1 ----
    unsigned* U = (unsigned*)C0;
    unsigned* T = ((unsigned*)C0) + 2048;
    float mf[8];
    #pragma unroll
    for (int k = 0; k < 4; ++k){
        int q = tid + k * 512;
        int i = q >> 5, wj = q & 31;
        int rr = 2 * i;
        const unsigned* H5w = (const unsigned*)H5s;
        unsigned m = pkmax(H5w[rr*32 + wj], H5w[(rr+1)*32 + wj]);
        if (rr >= 1) m = pkmax(m, H5w[(rr-1)*32 + wj]);
        if (rr >= 2) m = pkmax(m, H5w[(rr-2)*32 + wj]);
        if (rr + 2 <= 127) m = pkmax(m, H5w[(rr+2)*32 + wj]);
        U[q] = m;
        mf[2*k]   = q2 * bf2f((unsigned short)(m & 0xFFFFu));
        mf[2*k+1] = q2 * bf2f((unsigned short)(m >> 16));
    }
    __syncthreads();

    // ---- P6: 4x unscaled pool3 on 64x64; fold scales into M regs ----
    const float gs[4] = {q3, q4, q5, q6};
    #pragma unroll
    for (int it = 0; it < 4; ++it){
        #pragma unroll
        for (int k = 0; k < 4; ++k){
            int q = tid + k * 512;
            unsigned w = U[q];
            unsigned wl = __shfl_up(w, 1);
            unsigned wr = __shfl_down(w, 1);
            if ((q & 31) == 0)  wl = 0u;
            if ((q & 31) == 31) wr = 0u;
            T[q] = pkmax(pkmax(alignb(w, wl), w), alignb(wr, w));
        }
        __syncthreads();
        #pragma unroll
        for (int k = 0; k < 4; ++k){
            int q = tid + k * 512;
            int r = q >> 5;
            unsigned w = T[q];
            if (r > 0)  w = pkmax(w, T[q - 32]);
            if (r < 63) w = pkmax(w, T[q + 32]);
            U[q] = w;
            mf[2*k]   = fmaxf(mf[2*k],   gs[it] * bf2f((unsigned short)(w & 0xFFFFu)));
            mf[2*k+1] = fmaxf(mf[2*k+1], gs[it] * bf2f((unsigned short)(w >> 16)));
        }
        __syncthreads();
    }

    // ---- P7: write m64 from M regs ----
    {
        unsigned* mp = (unsigned*)(m64g + (size_t)bc * 4096);
        #pragma unroll
        for (int k = 0; k < 4; ++k){
            int q = tid + k * 512;
            mp[q] = cvtpk(mf[2*k], mf[2*k+1]);
        }
    }
}

// ============================ K3: scalar MLP, SGPR weights, zero LDS ============================
__global__ __launch_bounds__(256, 6) void k3_sgpr(
    const float* __restrict__ x,
    const unsigned short* __restrict__ outp, const unsigned short* __restrict__ m64,
    const float* __restrict__ W1T,   // [256][16] f32 (w1 transposed)
    const float* __restrict__ w2,    // [256][16] f32
    const float* __restrict__ b1, const float* __restrict__ b2,
    float* __restrict__ y)
{
    const int tid = threadIdx.x;
    const int blk = blockIdx.x;
    const int b = blk >> 6;
    const int t = blk & 63;

    const int pix = t * 256 + tid;
    const int mi = (pix >> 8) * 64 + ((pix & 127) >> 1);
    const size_t base = (size_t)b * 256 * HW_;
    const size_t mbase = (size_t)b * 256 * 4096;

    float h[16];
    #pragma unroll
    for (int m = 0; m < 16; ++m) h[m] = 0.0f;

    #pragma unroll 4
    for (int c = 0; c < 256; ++c){
        float o  = bf2f(outp[base + (size_t)c * HW_ + pix]);
        float mo = bf2f(m64[mbase + (size_t)c * 4096 + mi]);
        o = fmaxf(o, mo);
        const float4* wr = (const float4*)(W1T + c * 16);   // uniform -> s_load
        float4 a0 = wr[0], a1 = wr[1], a2 = wr[2], a3 = wr[3];
        h[0]  = fmaf(a0.x, o, h[0]);  h[1]  = fmaf(a0.y, o, h[1]);
        h[2]  = fmaf(a0.z, o, h[2]);  h[3]  = fmaf(a0.w, o, h[3]);
        h[4]  = fmaf(a1.x, o, h[4]);  h[5]  = fmaf(a1.y, o, h[5]);
        h[6]  = fmaf(a1.z, o, h[6]);  h[7]  = fmaf(a1.w, o, h[7]);
        h[8]  = fmaf(a2.x, o, h[8]);  h[9]  = fmaf(a2.y, o, h[9]);
        h[10] = fmaf(a2.z, o, h[10]); h[11] = fmaf(a2.w, o, h[11]);
        h[12] = fmaf(a3.x, o, h[12]); h[13] = fmaf(a3.y, o, h[13]);
        h[14] = fmaf(a3.z, o, h[14]); h[15] = fmaf(a3.w, o, h[15]);
    }
    #pragma unroll
    for (int m = 0; m < 16; ++m) h[m] = fmaxf(h[m] + b1[m], 0.0f);

    #pragma unroll 4
    for (int c = 0; c < 256; ++c){
        const float4* wr = (const float4*)(w2 + c * 16);    // uniform -> s_load
        float4 a0 = wr[0], a1 = wr[1], a2 = wr[2], a3 = wr[3];
        float acc = b2[c];
        acc += a0.x * h[0]  + a0.y * h[1]  + a0.z * h[2]  + a0.w * h[3];
        acc += a1.x * h[4]  + a1.y * h[5]  + a1.z * h[6]  + a1.w * h[7];
        acc += a2.x * h[8]  + a2.y * h[9]  + a2.z * h[10] + a2.w * h[11];
        acc += a3.x * h[12] + a3.y * h[13] + a3.z * h[14] + a3.w * h[15];
        float R = 1.0f / (1.0f + __expf(-acc));
        float xv = x[base + (size_t)c * HW_ + pix];
        y[base + (size_t)c * HW_ + pix] = xv * R;
    }
}

extern "C" void kernel_launch(void* const* d_in, const int* in_sizes, int n_in,
                              void* d_out, int out_size, void* d_ws, size_t ws_size,
                              hipStream_t stream) {
    const float* x  = (const float*)d_in[0];
    const float* w1 = (const float*)d_in[1];
    const float* b1 = (const float*)d_in[2];
    const float* w2 = (const float*)d_in[3];
    const float* b2 = (const float*)d_in[4];
    float* y  = (float*)d_out;
    char* ws = (char*)d_ws;

    unsigned short* outp = (unsigned short*)ws;                 // 134 MB
    unsigned short* m64  = (unsigned short*)(ws + 134217728);   // 33.5 MB
    float*          W1T  = (float*)(ws + 167772160);            // 16 KB

    float g1 = 0.99f;
    float q2 = (float)std::pow(0.99, 3.0);
    float q3 = (float)std::pow(0.99, 7.0);
    float q4 = (float)std::pow(0.99, 15.0);
    float q5 = (float)std::pow(0.99, 31.0);
    float q6 = (float)std::pow(0.99, 63.0);

    k0_prep<<<16, 256, 0, stream>>>(w1, W1T);
    k1f<<<4096, 512, 0, stream>>>(x, outp, m64, g1, q2, q3, q4, q5, q6);
    k3_sgpr<<<1024, 256, 0, stream>>>(x, outp, m64, W1T, w2, b1, b2, y);
}